// Round 15
// baseline (1123.769 us; speedup 1.0000x reference)
//
#include <hip/hip_runtime.h>
#include <hip/hip_fp16.h>

#define LATENT 32
#define NN     100000
#define E1N    3200000
#define N2N    200000
#define E2N    3200000
#define MN     131072
#define MAXX   100
#define EPSV   1e-5f

#define BK_SH     7          // 128 nodes per bucket
#define PACK_SH   20         // src in bits 0..19, dst_local in bits 20..26
#define PACK_MASK 0xFFFFF
#define NBKT1     782        // ceil(100000/128)
#define NBKT2     1563       // ceil(200000/128)
#define P_PART    128        // partitions per edge list
#define CH        25000      // edges per partition (3.2M / 128)
#define MF_       200064     // NBKT2*128
#define MTOT      500224     // 2*MF_ + NBKT1*128
#define SCAN_NB   245        // ceil(MTOT/2048)
#define ECAPW     4608       // LDS edge buffer for window-sort bcsr

// ---------------- workspace layout (bytes) ----------------
constexpr size_t OFF_HA    = 0;                   // 25.6MB region (be temps / hA fp16)
constexpr size_t OFF_HB    = 25600000;            // 25.6MB region (cnt / h1 / hB fp16)
constexpr size_t OFF_CSR1  = OFF_HB + 12800000;
constexpr size_t OFF_CSR2  = 51200000;
constexpr size_t OFF_CSR2R = 64000000;
constexpr size_t OFF_OFF1  = 76800000;
constexpr size_t OFF_OFF2  = OFF_OFF1 + 400128;
constexpr size_t OFF_OFF2R = OFF_OFF2 + 800128;
constexpr size_t OFF_BSUM  = OFF_OFF2R + 800128;
constexpr size_t OFF_HIST  = OFF_BSUM + 2048;
constexpr size_t OFF_WLP   = OFF_HIST + 512;
constexpr size_t OFF_WRP   = OFF_WLP + 4096;
constexpr size_t OFF_BP    = OFF_WRP + 4096;
constexpr size_t OFF_MARK  = OFF_BP + 256;        // N2N ints
// guarded tail (only used when ws_size >= WS_NEED)
constexpr size_t OFF_ACC   = 80000000;            // N2N*64 fp32 = 51.2MB
constexpr size_t OFF_W2F   = OFF_ACC  + 51200000; // 1563*512 ints = 3.2MB
constexpr size_t OFF_W2R   = OFF_W2F  + 3201024;
constexpr size_t OFF_INVF  = OFF_W2R  + 3201024;  // N2N fp32
constexpr size_t OFF_INVR  = OFF_INVF + 800000;
constexpr size_t OFF_BENDF = OFF_INVR + 800000;   // NBKT2 ints
constexpr size_t OFF_BENDR = OFF_BENDF + 8192;
constexpr size_t WS_NEED   = 139300000;

// ---------------- x histogram + fused GraphNorm/weight prep ----------------

__global__ void k_histx(const int* __restrict__ x, int* __restrict__ hist, int n) {
    __shared__ int h[128];
    int t = threadIdx.x;
    if (t < 128) h[t] = 0;
    __syncthreads();
    int stride = gridDim.x * blockDim.x;
    for (int i = blockIdx.x * blockDim.x + t; i < n; i += stride)
        atomicAdd(&h[x[i]], 1);
    __syncthreads();
    if (t < 128 && h[t] > 0) atomicAdd(&hist[t], h[t]);
}

__global__ void k_prep(const int* __restrict__ hist, const float* __restrict__ emb,
                       const float* __restrict__ gw, const float* __restrict__ gb,
                       const float* __restrict__ gms,
                       const float* __restrict__ wl, const float* __restrict__ bl,
                       const float* __restrict__ wr,
                       float* __restrict__ wlp, float* __restrict__ wrp,
                       float* __restrict__ bp) {
    __shared__ float A[32], B[32];
    int t = threadIdx.x;
    if (t < 32) {
        float m = 0.f, q = 0.f;
        for (int c = 0; c <= MAXX; ++c) {
            float hc = (float)hist[c];
            float v  = emb[c * 32 + t];
            m += hc * v; q += hc * v * v;
        }
        m *= (1.f / (float)NN); q *= (1.f / (float)NN);
        float ms  = gms[t];
        float var = q - 2.f * ms * m * m + ms * ms * m * m;
        float a   = gw[t] / sqrtf(var + EPSV);
        A[t] = a;
        B[t] = gb[t] - a * ms * m;
    }
    __syncthreads();
    for (int i = t; i < 1024; i += 256) {
        int k = i & 31;
        wlp[i] = wl[i] * A[k];
        wrp[i] = wr[i] * A[k];
    }
    if (t < 32) {
        float s = bl[t];
        for (int k = 0; k < 32; ++k) s += (wl[t * 32 + k] + wr[t * 32 + k]) * B[k];
        bp[t] = s;
    }
}

__global__ void k_mark(const int* __restrict__ pos2, int* __restrict__ mark, int m) {
    int idx = blockIdx.x * blockDim.x + threadIdx.x;
    int stride = gridDim.x * blockDim.x;
    for (; idx < m; idx += stride) mark[pos2[idx]] = 1;
}

// ---------------- partitioned counting-sort CSR build ----------------

__global__ void __launch_bounds__(256) k_hist(const int* __restrict__ dF,
                                              const int* __restrict__ dR,
                                              const int* __restrict__ d1,
                                              int* __restrict__ cnt) {
    __shared__ int hist[NBKT2];
    int t = threadIdx.x;
    int which = blockIdx.x >> 7, p = blockIdx.x & 127;
    const int* d; int nbkt, roff;
    if (which == 0)      { d = dF; nbkt = NBKT2; roff = 0; }
    else if (which == 1) { d = dR; nbkt = NBKT2; roff = MF_; }
    else                 { d = d1; nbkt = NBKT1; roff = 2 * MF_; }
    for (int b = t; b < nbkt; b += 256) hist[b] = 0;
    __syncthreads();
    int e0 = p * CH;
    for (int e = e0 + t; e < e0 + CH; e += 256)
        atomicAdd(&hist[d[e] >> BK_SH], 1);
    __syncthreads();
    for (int b = t; b < nbkt; b += 256) cnt[roff + (b << 7) + p] = hist[b];
}

__global__ void k_scanA(const int* __restrict__ cnt, int* __restrict__ bsum) {
    __shared__ int lds[256];
    int t = threadIdx.x;
    int base = blockIdx.x * 2048 + t * 8;
    int s = 0;
    #pragma unroll
    for (int j = 0; j < 8; ++j) { int e = base + j; if (e < MTOT) s += cnt[e]; }
    lds[t] = s; __syncthreads();
    for (int o = 128; o > 0; o >>= 1) { if (t < o) lds[t] += lds[t + o]; __syncthreads(); }
    if (t == 0) bsum[blockIdx.x] = lds[0];
}

__global__ void k_scanB(int* __restrict__ bsum, int nb) {
    __shared__ int lds[256];
    int t = threadIdx.x;
    int v = (t < nb) ? bsum[t] : 0;
    lds[t] = v; __syncthreads();
    for (int o = 1; o < 256; o <<= 1) {
        int add = (t >= o) ? lds[t - o] : 0;
        __syncthreads();
        lds[t] += add;
        __syncthreads();
    }
    if (t < nb) bsum[t] = lds[t] - v;
}

__global__ void k_scanC(int* __restrict__ cnt, const int* __restrict__ bsum) {
    __shared__ int lds[256];
    int t = threadIdx.x;
    int base = blockIdx.x * 2048 + t * 8;
    int v[8]; int run = 0;
    #pragma unroll
    for (int j = 0; j < 8; ++j) {
        int e = base + j;
        v[j] = (e < MTOT) ? cnt[e] : 0;
        run += v[j];
    }
    int tot = run;
    lds[t] = tot; __syncthreads();
    for (int o = 1; o < 256; o <<= 1) {
        int add = (t >= o) ? lds[t - o] : 0;
        __syncthreads();
        lds[t] += add;
        __syncthreads();
    }
    int ex = lds[t] - tot + bsum[blockIdx.x];
    #pragma unroll
    for (int j = 0; j < 8; ++j) {
        int e = base + j;
        if (e < MTOT) { cnt[e] = ex; ex += v[j]; }
    }
}

__global__ void __launch_bounds__(256) k_bfillFR(
    const int* __restrict__ sF, const int* __restrict__ dF,
    const int* __restrict__ sR, const int* __restrict__ dR,
    const int* __restrict__ cnt, int* __restrict__ beF, int* __restrict__ beR) {
    __shared__ int cur[NBKT2];
    int t = threadIdx.x;
    int which = blockIdx.x >> 7, p = blockIdx.x & 127;
    const int* s; const int* d; int* be; int roff, sub;
    if (which == 0) { s = sF; d = dF; be = beF; roff = 0;   sub = 0; }
    else            { s = sR; d = dR; be = beR; roff = MF_; sub = E2N; }
    for (int b = t; b < NBKT2; b += 256) cur[b] = cnt[roff + (b << 7) + p] - sub;
    __syncthreads();
    int e0 = p * CH;
    for (int e = e0 + t; e < e0 + CH; e += 256) {
        int dd  = d[e];
        int pos = atomicAdd(&cur[dd >> BK_SH], 1);
        be[pos] = s[e] | ((dd & 127) << PACK_SH);
    }
}

__global__ void __launch_bounds__(256) k_bfill1(
    const int* __restrict__ s1, const int* __restrict__ d1,
    const int* __restrict__ cnt, int* __restrict__ be) {
    __shared__ int cur[NBKT1];
    int t = threadIdx.x;
    int p = blockIdx.x;
    for (int b = t; b < NBKT1; b += 256) cur[b] = cnt[2 * MF_ + (b << 7) + p] - 2 * E2N;
    __syncthreads();
    int e0 = p * CH;
    for (int e = e0 + t; e < e0 + CH; e += 256) {
        int dd  = d1[e];
        int pos = atomicAdd(&cur[dd >> BK_SH], 1);
        be[pos] = s1[e] | ((dd & 127) << PACK_SH);
    }
}

// old per-bucket node-major refine (graph1 always; graph2 in fallback path)
__device__ __forceinline__ void bcsr_body(const int* __restrict__ bedge,
                                          const int* __restrict__ cnt, int roff, int sub,
                                          int* __restrict__ off, int* __restrict__ csr,
                                          int b, int nbkt, int ntot, int etot) {
    __shared__ int lcnt[128], exs[128], sc[128];
    int t  = threadIdx.x;
    int e0 = cnt[roff + (b << 7)] - sub;
    int e1 = (b + 1 < nbkt) ? cnt[roff + ((b + 1) << 7)] - sub : etot;
    int node0 = b << BK_SH;
    int nloc  = ntot - node0; if (nloc > 128) nloc = 128;
    if (t < 128) lcnt[t] = 0;
    __syncthreads();
    for (int e = e0 + t; e < e1; e += 256)
        atomicAdd(&lcnt[(bedge[e] >> PACK_SH) & 127], 1);
    __syncthreads();
    int cv = (t < 128) ? lcnt[t] : 0;
    if (t < 128) sc[t] = cv;
    __syncthreads();
    for (int o = 1; o < 128; o <<= 1) {
        int add = (t < 128 && t >= o) ? sc[t - o] : 0;
        __syncthreads();
        if (t < 128) sc[t] += add;
        __syncthreads();
    }
    if (t < 128) exs[t] = sc[t] - cv;
    __syncthreads();
    if (t < nloc) off[node0 + t] = e0 + exs[t];
    if (b == nbkt - 1 && t == 0) off[ntot] = e1;
    if (t < 128) lcnt[t] = 0;
    __syncthreads();
    for (int e = e0 + t; e < e1; e += 256) {
        int p   = bedge[e];
        int dl  = (p >> PACK_SH) & 127;
        int pos = e0 + exs[dl] + atomicAdd(&lcnt[dl], 1);
        csr[pos] = p & PACK_MASK;
    }
}

__global__ void __launch_bounds__(256) k_bcsr2(
    const int* beF, const int* beR, const int* __restrict__ cnt,
    int* offF, int* csrF, int* offR, int* csrR) {
    int b = blockIdx.x;
    if (b < NBKT2) bcsr_body(beF, cnt, 0,   0,   offF, csrF, b,         NBKT2, N2N, E2N);
    else           bcsr_body(beR, cnt, MF_, E2N, offR, csrR, b - NBKT2, NBKT2, N2N, E2N);
}

__global__ void __launch_bounds__(256) k_bcsr1(
    const int* be, const int* __restrict__ cnt, int* off, int* csr) {
    bcsr_body(be, cnt, 2 * MF_, 2 * E2N, off, csr, blockIdx.x, NBKT1, NN, E1N);
}

// window-major refine for graph2 (big-ws path): key = (win<<7)|dl, win = src>>16
__global__ void __launch_bounds__(256) k_bcsr2w(
    const int* beF, const int* beR, const int* __restrict__ cnt,
    int* csrF, int* csrR,
    int* __restrict__ w2F, int* __restrict__ w2R,
    float* __restrict__ invF, float* __restrict__ invR,
    int* __restrict__ bendF, int* __restrict__ bendR) {
    __shared__ int ebuf[ECAPW];
    __shared__ int kcnt[512];
    __shared__ int psum[256];
    int blk = blockIdx.x;
    const int* be; int* csr; int* w2; float* inv; int* bend; int roff, sub;
    if (blk < NBKT2) { be = beF; csr = csrF; w2 = w2F; inv = invF; bend = bendF; roff = 0;   sub = 0; }
    else { blk -= NBKT2; be = beR; csr = csrR; w2 = w2R; inv = invR; bend = bendR; roff = MF_; sub = E2N; }
    int b = blk;
    int t = threadIdx.x;
    int e0 = cnt[roff + (b << 7)] - sub;
    int e1 = (b + 1 < NBKT2) ? cnt[roff + ((b + 1) << 7)] - sub : E2N;
    int ne = e1 - e0;
    int node0 = b << BK_SH;
    int nloc = N2N - node0; if (nloc > 128) nloc = 128;   // OOB guard (round-14 crash fix)
    if (t == 0) bend[b] = e1;
    if (ne <= ECAPW) {
        for (int i = t; i < 512; i += 256) kcnt[i] = 0;
        __syncthreads();
        for (int e = t; e < ne; e += 256) {
            int v = be[e0 + e];
            ebuf[e] = v;
            int key = (((v & PACK_MASK) >> 16) << 7) | ((v >> PACK_SH) & 127);
            atomicAdd(&kcnt[key], 1);
        }
        __syncthreads();
        if (t < nloc) {
            int dg = kcnt[t] + kcnt[128 + t] + kcnt[256 + t] + kcnt[384 + t];
            inv[node0 + t] = 1.0f / (float)(dg > 0 ? dg : 1);
        }
        int v0 = kcnt[2 * t], v1 = kcnt[2 * t + 1];
        int tot = v0 + v1;
        psum[t] = tot;
        __syncthreads();
        for (int o = 1; o < 256; o <<= 1) {
            int add = (t >= o) ? psum[t - o] : 0;
            __syncthreads();
            psum[t] += add;
            __syncthreads();
        }
        int base = psum[t] - tot;
        kcnt[2 * t]     = base;
        kcnt[2 * t + 1] = base + v0;
        __syncthreads();
        {
            int key = t;
            w2[(b * 4 + (key >> 7)) * 128 + (key & 127)] = e0 + kcnt[key];
            key = t + 256;
            w2[(b * 4 + (key >> 7)) * 128 + (key & 127)] = e0 + kcnt[key];
        }
        __syncthreads();
        for (int e = t; e < ne; e += 256) {
            int v = ebuf[e];
            int key = (((v & PACK_MASK) >> 16) << 7) | ((v >> PACK_SH) & 127);
            int pos = atomicAdd(&kcnt[key], 1);
            csr[e0 + pos] = v & PACK_MASK;
        }
    } else {
        // fallback: node-major into window-0 segments (w>0 empty)
        int* lcnt = kcnt;
        int* sc   = kcnt + 128;
        int* exs  = kcnt + 256;
        if (t < 128) lcnt[t] = 0;
        __syncthreads();
        for (int e = e0 + t; e < e1; e += 256)
            atomicAdd(&lcnt[(be[e] >> PACK_SH) & 127], 1);
        __syncthreads();
        int cv = (t < 128) ? lcnt[t] : 0;
        if (t < nloc) inv[node0 + t] = 1.0f / (float)(cv > 0 ? cv : 1);
        if (t < 128) sc[t] = cv;
        __syncthreads();
        for (int o = 1; o < 128; o <<= 1) {
            int add = (t < 128 && t >= o) ? sc[t - o] : 0;
            __syncthreads();
            if (t < 128) sc[t] += add;
            __syncthreads();
        }
        if (t < 128) exs[t] = sc[t] - cv;
        __syncthreads();
        if (t < 128) {
            w2[(b * 4 + 0) * 128 + t] = e0 + exs[t];
            w2[(b * 4 + 1) * 128 + t] = e1;
            w2[(b * 4 + 2) * 128 + t] = e1;
            w2[(b * 4 + 3) * 128 + t] = e1;
        }
        if (t < 128) lcnt[t] = 0;
        __syncthreads();
        for (int e = e0 + t; e < e1; e += 256) {
            int p   = be[e];
            int dl  = (p >> PACK_SH) & 127;
            int pos = e0 + exs[dl] + atomicAdd(&lcnt[dl], 1);
            csr[pos] = p & PACK_MASK;
        }
    }
}

// ---------------- conv1 layer 1: LDS emb table, 4B x-gathers, fp16 out ----------------

__global__ void __launch_bounds__(256) k_sage_emb(
    const int* __restrict__ x, const float* __restrict__ emb,
    __half* __restrict__ hout,
    const int* __restrict__ csr, const int* __restrict__ off,
    const float* __restrict__ wlp, const float* __restrict__ bp,
    const float* __restrict__ wrp, int n) {
    __shared__ float embS[(MAXX + 1) * 32];
    __shared__ float wlT[32][33];
    __shared__ float wrT[32][33];
    int tid = threadIdx.x;
    for (int i = tid; i < (MAXX + 1) * 32; i += 256) embS[i] = emb[i];
    for (int i = tid; i < 1024; i += 256) {
        int j = i >> 5, k = i & 31;
        wlT[k][j] = wlp[i];
        wrT[k][j] = wrp[i];
    }
    __syncthreads();
    int lane = tid & 31;
    int g    = blockIdx.x * 8 + (tid >> 5);
    int G    = gridDim.x * 8;
    for (int node = g; node < n; node += G) {
        int s0 = off[node], s1 = off[node + 1];
        float a0 = 0.f, a1 = 0.f, a2 = 0.f, a3 = 0.f;
        for (int base = s0; base < s1; base += 32) {
            int e  = base + lane;
            int xv = x[csr[e < s1 ? e : s1 - 1]];
            int m  = s1 - base; if (m > 32) m = 32;
            for (int j = 0; j < m; j += 4) {
                #pragma unroll
                for (int k = 0; k < 4; ++k) {
                    int jj = j + k;
                    int xj = __shfl(xv, jj & 31, 32);
                    float v = embS[xj * 32 + lane];
                    float w = (jj < m) ? 1.f : 0.f;
                    switch (k) {
                        case 0: a0 = fmaf(v, w, a0); break;
                        case 1: a1 = fmaf(v, w, a1); break;
                        case 2: a2 = fmaf(v, w, a2); break;
                        case 3: a3 = fmaf(v, w, a3); break;
                    }
                }
            }
        }
        int c = s1 - s0;
        float s = ((a0 + a1) + (a2 + a3)) * (1.0f / (float)(c > 0 ? c : 1));
        float hs = embS[x[node] * 32 + lane];
        float acc = bp[lane];
        #pragma unroll
        for (int k = 0; k < 32; ++k) {
            acc = fmaf(__shfl(s, k, 32), wlT[k][lane], acc);
            acc = fmaf(__shfl(hs, k, 32), wrT[k][lane], acc);
        }
        hout[node * 32 + lane] = __float2half(fmaxf(acc, 0.f));
    }
}

// ---------------- dual-edge fp16 gather core (template slot width) ----------------

template<int SL>
__device__ __forceinline__ void seg4_raw(
    const __half2* __restrict__ h2,
    const int* __restrict__ cA, int a0, int a1,
    const int* __restrict__ cB, int b0, int b1,
    const int* __restrict__ cC, int c0, int c1,
    const int* __restrict__ cD, int d0, int d1,
    int lane,
    float& oEA, float& oOA, float& oEB, float& oOB,
    float& oEC, float& oOC, float& oED, float& oOD)
{
    float eA[2] = {0.f, 0.f}, oA[2] = {0.f, 0.f};
    float eB[2] = {0.f, 0.f}, oB[2] = {0.f, 0.f};
    float eC[2] = {0.f, 0.f}, oC[2] = {0.f, 0.f};
    float eD[2] = {0.f, 0.f}, oD[2] = {0.f, 0.f};
    int hsel = (lane >> 4) & 1;
    int col  = lane & 15;
    int pA = a0, pB = b0, pC = c0, pD = d0;
    while (pA < a1 || pB < b1 || pC < c1 || pD < d1) {
        int iA = 0, iB = 0, iC = 0, iD = 0, mA = 0, mB = 0, mC = 0, mD = 0;
        if (pA < a1) { int e = pA + lane; iA = cA[e < a1 ? e : a1 - 1]; mA = a1 - pA; if (mA > 32) mA = 32; }
        if (pB < b1) { int e = pB + lane; iB = cB[e < b1 ? e : b1 - 1]; mB = b1 - pB; if (mB > 32) mB = 32; }
        if (pC < c1) { int e = pC + lane; iC = cC[e < c1 ? e : c1 - 1]; mC = c1 - pC; if (mC > 32) mC = 32; }
        if (pD < d1) { int e = pD + lane; iD = cD[e < d1 ? e : d1 - 1]; mD = d1 - pD; if (mD > 32) mD = 32; }
        int mm = mA > mB ? mA : mB;
        if (mC > mm) mm = mC;
        if (mD > mm) mm = mD;
        for (int j = 0; j < mm; j += SL) {
            __half2 vA[SL / 2], vB[SL / 2], vC[SL / 2], vD[SL / 2];
            bool dA = j < mA, dB = j < mB, dC = j < mC, dD = j < mD;
            if (dA) {
                #pragma unroll
                for (int kk = 0; kk < SL / 2; ++kk) {
                    int es = j + 2 * kk + hsel;
                    vA[kk] = h2[__shfl(iA, es & 31, 32) * 16 + col];
                }
            }
            if (dB) {
                #pragma unroll
                for (int kk = 0; kk < SL / 2; ++kk) {
                    int es = j + 2 * kk + hsel;
                    vB[kk] = h2[__shfl(iB, es & 31, 32) * 16 + col];
                }
            }
            if (dC) {
                #pragma unroll
                for (int kk = 0; kk < SL / 2; ++kk) {
                    int es = j + 2 * kk + hsel;
                    vC[kk] = h2[__shfl(iC, es & 31, 32) * 16 + col];
                }
            }
            if (dD) {
                #pragma unroll
                for (int kk = 0; kk < SL / 2; ++kk) {
                    int es = j + 2 * kk + hsel;
                    vD[kk] = h2[__shfl(iD, es & 31, 32) * 16 + col];
                }
            }
            if (dA) {
                #pragma unroll
                for (int kk = 0; kk < SL / 2; ++kk) {
                    int es = j + 2 * kk + hsel;
                    float w = (es < mA) ? 1.f : 0.f;
                    float2 f = __half22float2(vA[kk]);
                    eA[kk & 1] = fmaf(f.x, w, eA[kk & 1]);
                    oA[kk & 1] = fmaf(f.y, w, oA[kk & 1]);
                }
            }
            if (dB) {
                #pragma unroll
                for (int kk = 0; kk < SL / 2; ++kk) {
                    int es = j + 2 * kk + hsel;
                    float w = (es < mB) ? 1.f : 0.f;
                    float2 f = __half22float2(vB[kk]);
                    eB[kk & 1] = fmaf(f.x, w, eB[kk & 1]);
                    oB[kk & 1] = fmaf(f.y, w, oB[kk & 1]);
                }
            }
            if (dC) {
                #pragma unroll
                for (int kk = 0; kk < SL / 2; ++kk) {
                    int es = j + 2 * kk + hsel;
                    float w = (es < mC) ? 1.f : 0.f;
                    float2 f = __half22float2(vC[kk]);
                    eC[kk & 1] = fmaf(f.x, w, eC[kk & 1]);
                    oC[kk & 1] = fmaf(f.y, w, oC[kk & 1]);
                }
            }
            if (dD) {
                #pragma unroll
                for (int kk = 0; kk < SL / 2; ++kk) {
                    int es = j + 2 * kk + hsel;
                    float w = (es < mD) ? 1.f : 0.f;
                    float2 f = __half22float2(vD[kk]);
                    eD[kk & 1] = fmaf(f.x, w, eD[kk & 1]);
                    oD[kk & 1] = fmaf(f.y, w, oD[kk & 1]);
                }
            }
        }
        pA += 32; pB += 32; pC += 32; pD += 32;
    }
    float sE, sO;
    sE = eA[0] + eA[1]; sE += __shfl_xor(sE, 16, 32);
    sO = oA[0] + oA[1]; sO += __shfl_xor(sO, 16, 32);
    oEA = sE; oOA = sO;
    sE = eB[0] + eB[1]; sE += __shfl_xor(sE, 16, 32);
    sO = oB[0] + oB[1]; sO += __shfl_xor(sO, 16, 32);
    oEB = sE; oOB = sO;
    sE = eC[0] + eC[1]; sE += __shfl_xor(sE, 16, 32);
    sO = oC[0] + oC[1]; sO += __shfl_xor(sO, 16, 32);
    oEC = sE; oOC = sO;
    sE = eD[0] + eD[1]; sE += __shfl_xor(sE, 16, 32);
    sO = oD[0] + oD[1]; sO += __shfl_xor(sO, 16, 32);
    oED = sE; oOD = sO;
}

// mean wrapper (old path / graph1)
__device__ __forceinline__ void seg4_h2(
    const __half2* __restrict__ h2,
    const int* __restrict__ cA, int a0, int a1,
    const int* __restrict__ cB, int b0, int b1,
    const int* __restrict__ cC, int c0, int c1,
    const int* __restrict__ cD, int d0, int d1,
    int lane,
    float& oEA, float& oOA, float& oEB, float& oOB,
    float& oEC, float& oOC, float& oED, float& oOD)
{
    seg4_raw<16>(h2, cA, a0, a1, cB, b0, b1, cC, c0, c1, cD, d0, d1,
                 lane, oEA, oOA, oEB, oOB, oEC, oOC, oED, oOD);
    int nA = a1 - a0, nB = b1 - b0, nC = c1 - c0, nD = d1 - d0;
    float vA = 1.f / (float)(nA > 0 ? nA : 1);
    float vB = 1.f / (float)(nB > 0 ? nB : 1);
    float vC = 1.f / (float)(nC > 0 ? nC : 1);
    float vD = 1.f / (float)(nD > 0 ? nD : 1);
    oEA *= vA; oOA *= vA; oEB *= vB; oOB *= vB;
    oEC *= vC; oOC *= vC; oED *= vD; oOD *= vD;
}

// ---------------- sage kernels (fp16 tables, dual-edge gathers) ----------------

__global__ void __launch_bounds__(256) k_sage(
    const __half* __restrict__ hin, __half* __restrict__ hout,
    const int* __restrict__ csr, const int* __restrict__ off,
    const float* __restrict__ wl, const float* __restrict__ bl, const float* __restrict__ wr,
    int n) {
    __shared__ float wlT[32][33];
    __shared__ float wrT[32][33];
    int tid = threadIdx.x;
    for (int idx = tid; idx < 1024; idx += 256) {
        int j = idx >> 5, k = idx & 31;
        wlT[k][j] = wl[idx];
        wrT[k][j] = wr[idx];
    }
    __syncthreads();
    const __half2* h2 = (const __half2*)hin;
    int lane = tid & 31;
    int g    = blockIdx.x * 8 + (tid >> 5);
    int G    = gridDim.x * 8;
    for (int i = 4 * g; i < n; i += 4 * G) {
        int n0 = i, n1 = i + 1, n2 = i + 2, n3 = i + 3;
        float sE0, sO0, sE1, sO1, sE2, sO2, sE3, sO3;
        seg4_h2(h2, csr, off[n0], off[n0 + 1], csr, off[n1], off[n1 + 1],
                csr, off[n2], off[n2 + 1], csr, off[n3], off[n3 + 1],
                lane, sE0, sO0, sE1, sO1, sE2, sO2, sE3, sO3);
        float h0 = __half2float(hin[n0 * 32 + lane]);
        float h1 = __half2float(hin[n1 * 32 + lane]);
        float h2f = __half2float(hin[n2 * 32 + lane]);
        float h3 = __half2float(hin[n3 * 32 + lane]);
        float bb = bl[lane];
        float A0 = bb, A1 = bb, A2 = bb, A3 = bb;
        #pragma unroll
        for (int k = 0; k < 32; ++k) {
            float wlk = wlT[k][lane], wrk = wrT[k][lane];
            float s0k = __shfl((k & 1) ? sO0 : sE0, k >> 1, 32);
            float s1k = __shfl((k & 1) ? sO1 : sE1, k >> 1, 32);
            float s2k = __shfl((k & 1) ? sO2 : sE2, k >> 1, 32);
            float s3k = __shfl((k & 1) ? sO3 : sE3, k >> 1, 32);
            A0 = fmaf(s0k, wlk, A0);
            A0 = fmaf(__shfl(h0, k, 32), wrk, A0);
            A1 = fmaf(s1k, wlk, A1);
            A1 = fmaf(__shfl(h1, k, 32), wrk, A1);
            A2 = fmaf(s2k, wlk, A2);
            A2 = fmaf(__shfl(h2f, k, 32), wrk, A2);
            A3 = fmaf(s3k, wlk, A3);
            A3 = fmaf(__shfl(h3, k, 32), wrk, A3);
        }
        hout[n0 * 32 + lane] = __float2half(fmaxf(A0, 0.f));
        hout[n1 * 32 + lane] = __float2half(fmaxf(A1, 0.f));
        hout[n2 * 32 + lane] = __float2half(fmaxf(A2, 0.f));
        hout[n3 * 32 + lane] = __float2half(fmaxf(A3, 0.f));
    }
}

// old fused dual-direction sage (fallback path)
__global__ void __launch_bounds__(256) k_sage2(
    const __half* __restrict__ hin, __half* __restrict__ hout,
    const int* __restrict__ csrF, const int* __restrict__ offF,
    const int* __restrict__ csrR, const int* __restrict__ offR,
    const float* __restrict__ wlF, const float* __restrict__ blF, const float* __restrict__ wrF,
    const float* __restrict__ wlR, const float* __restrict__ blR, const float* __restrict__ wrR,
    const int* __restrict__ mask, int n) {
    __shared__ float WLF[32][33], WRF[32][33], WLR[32][33], WRR[32][33];
    int tid = threadIdx.x;
    for (int idx = tid; idx < 1024; idx += 256) {
        int j = idx >> 5, k = idx & 31;
        WLF[k][j] = wlF[idx];
        WRF[k][j] = wrF[idx];
        WLR[k][j] = wlR[idx];
        WRR[k][j] = wrR[idx];
    }
    __syncthreads();
    const __half2* h2 = (const __half2*)hin;
    int lane = tid & 31;
    int g    = blockIdx.x * 8 + (tid >> 5);
    int G    = gridDim.x * 8;
    for (int i = 2 * g; i < n; i += 2 * G) {
        int n0 = i, n1 = i + 1;
        int m0 = mask ? mask[n0] : 1;
        int m1 = mask ? mask[n1] : 1;
        if (!(m0 | m1)) continue;
        int f00 = offF[n0], f01 = offF[n0 + 1], r00 = offR[n0], r01 = offR[n0 + 1];
        int f10 = offF[n1], f11 = offF[n1 + 1], r10 = offR[n1], r11 = offR[n1 + 1];
        if (!m0) { f01 = f00; r01 = r00; }
        if (!m1) { f11 = f10; r11 = r10; }
        float sEF0, sOF0, sER0, sOR0, sEF1, sOF1, sER1, sOR1;
        seg4_h2(h2, csrF, f00, f01, csrR, r00, r01,
                csrF, f10, f11, csrR, r10, r11,
                lane, sEF0, sOF0, sER0, sOR0, sEF1, sOF1, sER1, sOR1);
        float bF = blF[lane], bR = blR[lane];
        if (m0) {
            float h0 = __half2float(hin[n0 * 32 + lane]);
            float aF0 = bF, aR0 = bR;
            #pragma unroll
            for (int k = 0; k < 32; ++k) {
                float fk = __shfl((k & 1) ? sOF0 : sEF0, k >> 1, 32);
                float rk = __shfl((k & 1) ? sOR0 : sER0, k >> 1, 32);
                float hk = __shfl(h0, k, 32);
                aF0 = fmaf(fk, WLF[k][lane], aF0);
                aF0 = fmaf(hk, WRF[k][lane], aF0);
                aR0 = fmaf(rk, WLR[k][lane], aR0);
                aR0 = fmaf(hk, WRR[k][lane], aR0);
            }
            hout[n0 * 32 + lane] = __float2half(fmaxf(aF0, 0.f) + fmaxf(aR0, 0.f));
        }
        if (m1) {
            float h1 = __half2float(hin[n1 * 32 + lane]);
            float aF1 = bF, aR1 = bR;
            #pragma unroll
            for (int k = 0; k < 32; ++k) {
                float fk = __shfl((k & 1) ? sOF1 : sEF1, k >> 1, 32);
                float rk = __shfl((k & 1) ? sOR1 : sER1, k >> 1, 32);
                float hk = __shfl(h1, k, 32);
                aF1 = fmaf(fk, WLF[k][lane], aF1);
                aF1 = fmaf(hk, WRF[k][lane], aF1);
                aR1 = fmaf(rk, WLR[k][lane], aR1);
                aR1 = fmaf(hk, WRR[k][lane], aR1);
            }
            hout[n1 * 32 + lane] = __float2half(fmaxf(aF1, 0.f) + fmaxf(aR1, 0.f));
        }
    }
}

// ---------------- window-pass conv2 (big-ws path) ----------------

__device__ __forceinline__ void segbounds(const int* __restrict__ w2,
                                          const int* __restrict__ bend,
                                          int n, int w, int& s, int& e) {
    int b = n >> 7, dl = n & 127;
    int idx = (b * 4 + w) * 128 + dl;
    s = w2[idx];
    e = (w * 128 + dl == 511) ? bend[b] : w2[idx + 1];
}

__global__ void __launch_bounds__(256) k_pass2(
    const __half* __restrict__ hin, float* __restrict__ acc,
    const int* __restrict__ csrF, const int* __restrict__ w2F, const int* __restrict__ bendF,
    const int* __restrict__ csrR, const int* __restrict__ w2R, const int* __restrict__ bendR,
    const int* __restrict__ mask, int w, int n) {
    const __half2* h2 = (const __half2*)hin;
    int tid = threadIdx.x;
    int lane = tid & 31;
    int g = blockIdx.x * 8 + (tid >> 5);
    int G = gridDim.x * 8;
    for (int i = 2 * g; i < n; i += 2 * G) {
        int n0 = i, n1 = i + 1;
        int m0 = mask ? mask[n0] : 1;
        int m1 = mask ? mask[n1] : 1;
        if (!(m0 | m1)) continue;
        int f00, f01, r00, r01, f10, f11, r10, r11;
        segbounds(w2F, bendF, n0, w, f00, f01);
        segbounds(w2R, bendR, n0, w, r00, r01);
        segbounds(w2F, bendF, n1, w, f10, f11);
        segbounds(w2R, bendR, n1, w, r10, r11);
        if (!m0) { f01 = f00; r01 = r00; }
        if (!m1) { f11 = f10; r11 = r10; }
        float sEF0, sOF0, sER0, sOR0, sEF1, sOF1, sER1, sOR1;
        seg4_raw<4>(h2, csrF, f00, f01, csrR, r00, r01,
                    csrF, f10, f11, csrR, r10, r11,
                    lane, sEF0, sOF0, sER0, sOR0, sEF1, sOF1, sER1, sOR1);
        int c = lane & 15;
        bool lo = lane < 16;
        if (m0 && lo) {
            float* a = acc + (size_t)n0 * 64;
            if (w) { sEF0 += a[c]; sOF0 += a[16 + c]; sER0 += a[32 + c]; sOR0 += a[48 + c]; }
            a[c] = sEF0; a[16 + c] = sOF0; a[32 + c] = sER0; a[48 + c] = sOR0;
        }
        if (m1 && lo) {
            float* a = acc + (size_t)n1 * 64;
            if (w) { sEF1 += a[c]; sOF1 += a[16 + c]; sER1 += a[32 + c]; sOR1 += a[48 + c]; }
            a[c] = sEF1; a[16 + c] = sOF1; a[32 + c] = sER1; a[48 + c] = sOR1;
        }
    }
}

__global__ void __launch_bounds__(256) k_epi2(
    const float* __restrict__ acc, const __half* __restrict__ hin, __half* __restrict__ hout,
    const float* __restrict__ invF, const float* __restrict__ invR,
    const float* __restrict__ wlF, const float* __restrict__ blF, const float* __restrict__ wrF,
    const float* __restrict__ wlR, const float* __restrict__ blR, const float* __restrict__ wrR,
    const int* __restrict__ mask, int n) {
    __shared__ float WLF[32][33], WRF[32][33], WLR[32][33], WRR[32][33];
    int tid = threadIdx.x;
    for (int i2 = tid; i2 < 1024; i2 += 256) {
        int j = i2 >> 5, k = i2 & 31;
        WLF[k][j] = wlF[i2];
        WRF[k][j] = wrF[i2];
        WLR[k][j] = wlR[i2];
        WRR[k][j] = wrR[i2];
    }
    __syncthreads();
    int lane = tid & 31;
    int g = blockIdx.x * 8 + (tid >> 5);
    int G = gridDim.x * 8;
    for (int node = g; node < n; node += G) {
        if (mask && !mask[node]) continue;
        const float* a = acc + (size_t)node * 64;
        int c = lane & 15;
        float iF = invF[node], iR = invR[node];
        float sEF = a[c] * iF, sOF = a[16 + c] * iF;
        float sER = a[32 + c] * iR, sOR = a[48 + c] * iR;
        float hs = __half2float(hin[node * 32 + lane]);
        float aF = blF[lane], aR = blR[lane];
        #pragma unroll
        for (int k = 0; k < 32; ++k) {
            float fk = __shfl((k & 1) ? sOF : sEF, k >> 1, 32);
            float rk = __shfl((k & 1) ? sOR : sER, k >> 1, 32);
            float hk = __shfl(hs, k, 32);
            aF = fmaf(fk, WLF[k][lane], aF);
            aF = fmaf(hk, WRF[k][lane], aF);
            aR = fmaf(rk, WLR[k][lane], aR);
            aR = fmaf(hk, WRR[k][lane], aR);
        }
        hout[node * 32 + lane] = __float2half(fmaxf(aF, 0.f) + fmaxf(aR, 0.f));
    }
}

__global__ void k_pair(const __half* __restrict__ h, const int* __restrict__ pos1,
                       __half* __restrict__ hp, int total) {
    int idx = blockIdx.x * blockDim.x + threadIdx.x;
    int stride = gridDim.x * blockDim.x;
    for (; idx < total; idx += stride) {
        int r = idx >> 5, k = idx & 31;
        int a = pos1[2 * r], b = pos1[2 * r + 1];
        hp[idx] = __float2half(__half2float(h[a * 32 + k]) * __half2float(h[b * 32 + k]));
    }
}

__global__ void k_final(const __half* __restrict__ h, const int* __restrict__ pos2,
                        const float* __restrict__ pw, const float* __restrict__ pb,
                        float* __restrict__ out, int m2) {
    int tid  = threadIdx.x;
    int lane = tid & 31;
    int i    = blockIdx.x * 8 + (tid >> 5);
    if (i >= m2) return;
    int p0 = pos2[2 * i], p1 = pos2[2 * i + 1];
    float v = __half2float(h[p0 * 32 + lane]) * __half2float(h[p1 * 32 + lane]) * pw[lane];
    #pragma unroll
    for (int o = 16; o > 0; o >>= 1) v += __shfl_xor(v, o, 32);
    if (lane == 0) out[i] = v + pb[0];
}

// ---------------- launch ----------------

extern "C" void kernel_launch(void* const* d_in, const int* in_sizes, int n_in,
                              void* d_out, int out_size, void* d_ws, size_t ws_size,
                              hipStream_t stream) {
    const int*   x      = (const int*)d_in[0];
    const int*   edge1  = (const int*)d_in[2];
    const int*   edge2  = (const int*)d_in[3];
    const int*   edge2r = (const int*)d_in[4];
    const int*   pos1   = (const int*)d_in[5];
    const int*   pos2   = (const int*)d_in[6];
    const float* emb    = (const float*)d_in[7];
    const float* gw     = (const float*)d_in[8];
    const float* gb     = (const float*)d_in[9];
    const float* gms    = (const float*)d_in[10];
    const float* c1wl   = (const float*)d_in[11];
    const float* c1bl   = (const float*)d_in[12];
    const float* c1wr   = (const float*)d_in[13];
    const float* c2wl   = (const float*)d_in[14];
    const float* c2bl   = (const float*)d_in[15];
    const float* c2wr   = (const float*)d_in[16];
    const float* c2rwl  = (const float*)d_in[17];
    const float* c2rbl  = (const float*)d_in[18];
    const float* c2rwr  = (const float*)d_in[19];
    const float* pw     = (const float*)d_in[20];
    const float* pb     = (const float*)d_in[21];
    float* out = (float*)d_out;

    char* ws = (char*)d_ws;
    __half* hA   = (__half*)(ws + OFF_HA);
    __half* hB   = (__half*)(ws + OFF_HB);
    int*   cnt   = (int*)(ws + OFF_HB);
    int*   csr1  = (int*)(ws + OFF_CSR1);
    int*   csr2  = (int*)(ws + OFF_CSR2);
    int*   csr2r = (int*)(ws + OFF_CSR2R);
    int*   off1  = (int*)(ws + OFF_OFF1);
    int*   off2  = (int*)(ws + OFF_OFF2);
    int*   off2r = (int*)(ws + OFF_OFF2R);
    int*   bsum  = (int*)(ws + OFF_BSUM);
    int*   hist  = (int*)(ws + OFF_HIST);
    float* wlp   = (float*)(ws + OFF_WLP);
    float* wrp   = (float*)(ws + OFF_WRP);
    float* bp    = (float*)(ws + OFF_BP);
    int*   mark  = (int*)(ws + OFF_MARK);
    // guarded tail
    float* accb  = (float*)(ws + OFF_ACC);
    int*   w2F   = (int*)(ws + OFF_W2F);
    int*   w2R   = (int*)(ws + OFF_W2R);
    float* invF  = (float*)(ws + OFF_INVF);
    float* invR  = (float*)(ws + OFF_INVR);
    int*   bendF = (int*)(ws + OFF_BENDF);
    int*   bendR = (int*)(ws + OFF_BENDR);

    const bool big = (ws_size >= WS_NEED);

    int* beF = (int*)(ws + OFF_HA);
    int* beR = (int*)(ws + OFF_HA + 12800000);
    int* be1 = (int*)(ws + OFF_HA);

    hipMemsetAsync(hist, 0, 512, stream);
    hipMemsetAsync(mark, 0, N2N * sizeof(int), stream);

    // --- GraphNorm stats + layer-1 weight fold; pos2 mark ---
    k_histx<<<256, 256, 0, stream>>>(x, hist, NN);
    k_prep<<<1, 256, 0, stream>>>(hist, emb, gw, gb, gms, c1wl, c1bl, c1wr, wlp, wrp, bp);
    k_mark<<<256, 256, 0, stream>>>(pos2, mark, MN);

    // --- CSR build front end ---
    k_hist<<<3 * P_PART, 256, 0, stream>>>(edge2 + E2N, edge2r + E2N, edge1 + E1N, cnt);
    k_scanA<<<SCAN_NB, 256, 0, stream>>>(cnt, bsum);
    k_scanB<<<1, 256, 0, stream>>>(bsum, SCAN_NB);
    k_scanC<<<SCAN_NB, 256, 0, stream>>>(cnt, bsum);
    k_bfillFR<<<2 * P_PART, 256, 0, stream>>>(edge2, edge2 + E2N, edge2r, edge2r + E2N,
                                              cnt, beF, beR);
    if (big) {
        k_bcsr2w<<<2 * NBKT2, 256, 0, stream>>>(beF, beR, cnt, csr2, csr2r,
                                                w2F, w2R, invF, invR, bendF, bendR);
    } else {
        k_bcsr2<<<2 * NBKT2, 256, 0, stream>>>(beF, beR, cnt, off2, csr2, off2r, csr2r);
    }
    k_bfill1<<<P_PART, 256, 0, stream>>>(edge1, edge1 + E1N, cnt, be1);
    k_bcsr1<<<NBKT1, 256, 0, stream>>>(be1, cnt, off1, csr1);

    // --- conv1 ---
    k_sage_emb<<<6250, 256, 0, stream>>>(x, emb, hB, csr1, off1, wlp, bp, wrp, NN);
    k_sage<<<2048, 256, 0, stream>>>(hB, hA, csr1, off1,
                                     c1wl + 1024, c1bl + 32, c1wr + 1024, NN);

    // --- pair features ---
    k_pair<<<2048, 256, 0, stream>>>(hA, pos1, hB, N2N * 32);

    // --- conv2 ---
    if (big) {
        for (int w = 0; w < 4; ++w)
            k_pass2<<<2048, 256, 0, stream>>>(hB, accb, csr2, w2F, bendF,
                                              csr2r, w2R, bendR, (const int*)nullptr, w, N2N);
        k_epi2<<<2048, 256, 0, stream>>>(accb, hB, hA, invF, invR,
            c2wl, c2bl, c2wr, c2rwl, c2rbl, c2rwr, (const int*)nullptr, N2N);
        for (int w = 0; w < 4; ++w)
            k_pass2<<<2048, 256, 0, stream>>>(hA, accb, csr2, w2F, bendF,
                                              csr2r, w2R, bendR, mark, w, N2N);
        k_epi2<<<2048, 256, 0, stream>>>(accb, hA, hB, invF, invR,
            c2wl + 1024, c2bl + 32, c2wr + 1024, c2rwl + 1024, c2rbl + 32, c2rwr + 1024,
            mark, N2N);
    } else {
        k_sage2<<<2048, 256, 0, stream>>>(hB, hA, csr2, off2, csr2r, off2r,
            c2wl, c2bl, c2wr, c2rwl, c2rbl, c2rwr, (const int*)nullptr, N2N);
        k_sage2<<<2048, 256, 0, stream>>>(hA, hB, csr2, off2, csr2r, off2r,
            c2wl + 1024, c2bl + 32, c2wr + 1024, c2rwl + 1024, c2rbl + 32, c2rwr + 1024,
            mark, N2N);
    }

    // --- head ---
    k_final<<<(MN / 2) / 8, 256, 0, stream>>>(hB, pos2, pw, pb, out, MN / 2);
}

// Round 16
// 790.988 us; speedup vs baseline: 1.4207x; 1.4207x over previous
//
#include <hip/hip_runtime.h>
#include <hip/hip_fp16.h>

#define LATENT 32
#define NN     100000
#define E1N    3200000
#define N2N    200000
#define E2N    3200000
#define MN     131072
#define MAXX   100
#define EPSV   1e-5f

#define BK_SH     7          // 128 nodes per bucket
#define PACK_SH   20         // src in bits 0..19, dst_local in bits 20..26
#define PACK_MASK 0xFFFFF
#define NBKT1     782        // ceil(100000/128)
#define NBKT2     1563       // ceil(200000/128)
#define P_PART    512        // partitions per edge list (4x round-13: occupancy fix)
#define CH        6250       // edges per partition (3.2M / 512)
#define MF_       800256     // NBKT2*512
#define MTOT      2000896    // 2*MF_ + NBKT1*512
#define SCAN_NB   977        // ceil(MTOT/2048)

// ---------------- workspace layout (bytes) ----------------
constexpr size_t OFF_HA    = 0;                   // 25.6MB region (be temps / hA fp16)
constexpr size_t OFF_HB    = 25600000;            // 25.6MB region (cnt 8MB / h1 / hB fp16)
constexpr size_t OFF_CSR1  = OFF_HB + 12800000;
constexpr size_t OFF_CSR2  = 51200000;
constexpr size_t OFF_CSR2R = 64000000;
constexpr size_t OFF_OFF1  = 76800000;
constexpr size_t OFF_OFF2  = OFF_OFF1 + 400128;
constexpr size_t OFF_OFF2R = OFF_OFF2 + 800128;
constexpr size_t OFF_BSUM  = OFF_OFF2R + 800128;  // 977 ints
constexpr size_t OFF_HIST  = OFF_BSUM + 4096;
constexpr size_t OFF_WLP   = OFF_HIST + 512;
constexpr size_t OFF_WRP   = OFF_WLP + 4096;
constexpr size_t OFF_BP    = OFF_WRP + 4096;
constexpr size_t OFF_MARK  = OFF_BP + 256;        // N2N ints

// ---------------- x histogram + fused GraphNorm/weight prep ----------------

__global__ void k_histx(const int* __restrict__ x, int* __restrict__ hist, int n) {
    __shared__ int h[128];
    int t = threadIdx.x;
    if (t < 128) h[t] = 0;
    __syncthreads();
    int stride = gridDim.x * blockDim.x;
    for (int i = blockIdx.x * blockDim.x + t; i < n; i += stride)
        atomicAdd(&h[x[i]], 1);
    __syncthreads();
    if (t < 128 && h[t] > 0) atomicAdd(&hist[t], h[t]);
}

__global__ void k_prep(const int* __restrict__ hist, const float* __restrict__ emb,
                       const float* __restrict__ gw, const float* __restrict__ gb,
                       const float* __restrict__ gms,
                       const float* __restrict__ wl, const float* __restrict__ bl,
                       const float* __restrict__ wr,
                       float* __restrict__ wlp, float* __restrict__ wrp,
                       float* __restrict__ bp) {
    __shared__ float A[32], B[32];
    int t = threadIdx.x;
    if (t < 32) {
        float m = 0.f, q = 0.f;
        for (int c = 0; c <= MAXX; ++c) {
            float hc = (float)hist[c];
            float v  = emb[c * 32 + t];
            m += hc * v; q += hc * v * v;
        }
        m *= (1.f / (float)NN); q *= (1.f / (float)NN);
        float ms  = gms[t];
        float var = q - 2.f * ms * m * m + ms * ms * m * m;
        float a   = gw[t] / sqrtf(var + EPSV);
        A[t] = a;
        B[t] = gb[t] - a * ms * m;
    }
    __syncthreads();
    for (int i = t; i < 1024; i += 256) {
        int k = i & 31;
        wlp[i] = wl[i] * A[k];
        wrp[i] = wr[i] * A[k];
    }
    if (t < 32) {
        float s = bl[t];
        for (int k = 0; k < 32; ++k) s += (wl[t * 32 + k] + wr[t * 32 + k]) * B[k];
        bp[t] = s;
    }
}

__global__ void k_mark(const int* __restrict__ pos2, int* __restrict__ mark, int m) {
    int idx = blockIdx.x * blockDim.x + threadIdx.x;
    int stride = gridDim.x * blockDim.x;
    for (; idx < m; idx += stride) mark[pos2[idx]] = 1;
}

// ---------------- partitioned counting-sort CSR build ----------------
// cnt layout: [list][bucket][partition] with partition stride 512

__global__ void __launch_bounds__(256) k_hist(const int* __restrict__ dF,
                                              const int* __restrict__ dR,
                                              const int* __restrict__ d1,
                                              int* __restrict__ cnt) {
    __shared__ int hist[NBKT2];
    int t = threadIdx.x;
    int which = blockIdx.x >> 9, p = blockIdx.x & 511;
    const int* d; int nbkt, roff;
    if (which == 0)      { d = dF; nbkt = NBKT2; roff = 0; }
    else if (which == 1) { d = dR; nbkt = NBKT2; roff = MF_; }
    else                 { d = d1; nbkt = NBKT1; roff = 2 * MF_; }
    for (int b = t; b < nbkt; b += 256) hist[b] = 0;
    __syncthreads();
    int e0 = p * CH;
    for (int e = e0 + t; e < e0 + CH; e += 256)
        atomicAdd(&hist[d[e] >> BK_SH], 1);
    __syncthreads();
    for (int b = t; b < nbkt; b += 256) cnt[roff + (b << 9) + p] = hist[b];
}

__global__ void k_scanA(const int* __restrict__ cnt, int* __restrict__ bsum) {
    __shared__ int lds[256];
    int t = threadIdx.x;
    int base = blockIdx.x * 2048 + t * 8;
    int s = 0;
    #pragma unroll
    for (int j = 0; j < 8; ++j) { int e = base + j; if (e < MTOT) s += cnt[e]; }
    lds[t] = s; __syncthreads();
    for (int o = 128; o > 0; o >>= 1) { if (t < o) lds[t] += lds[t + o]; __syncthreads(); }
    if (t == 0) bsum[blockIdx.x] = lds[0];
}

// exclusive scan of up to 1024 block sums (4 per thread)
__global__ void k_scanB(int* __restrict__ bsum, int nb) {
    __shared__ int lds[256];
    int t = threadIdx.x;
    int v[4]; int run = 0;
    #pragma unroll
    for (int j = 0; j < 4; ++j) {
        int e = t * 4 + j;
        v[j] = (e < nb) ? bsum[e] : 0;
        run += v[j];
    }
    int tot = run;
    lds[t] = tot; __syncthreads();
    for (int o = 1; o < 256; o <<= 1) {
        int add = (t >= o) ? lds[t - o] : 0;
        __syncthreads();
        lds[t] += add;
        __syncthreads();
    }
    int ex = lds[t] - tot;
    #pragma unroll
    for (int j = 0; j < 4; ++j) {
        int e = t * 4 + j;
        if (e < nb) { bsum[e] = ex; ex += v[j]; }
    }
}

__global__ void k_scanC(int* __restrict__ cnt, const int* __restrict__ bsum) {
    __shared__ int lds[256];
    int t = threadIdx.x;
    int base = blockIdx.x * 2048 + t * 8;
    int v[8]; int run = 0;
    #pragma unroll
    for (int j = 0; j < 8; ++j) {
        int e = base + j;
        v[j] = (e < MTOT) ? cnt[e] : 0;
        run += v[j];
    }
    int tot = run;
    lds[t] = tot; __syncthreads();
    for (int o = 1; o < 256; o <<= 1) {
        int add = (t >= o) ? lds[t - o] : 0;
        __syncthreads();
        lds[t] += add;
        __syncthreads();
    }
    int ex = lds[t] - tot + bsum[blockIdx.x];
    #pragma unroll
    for (int j = 0; j < 8; ++j) {
        int e = base + j;
        if (e < MTOT) { cnt[e] = ex; ex += v[j]; }
    }
}

__global__ void __launch_bounds__(256) k_bfillFR(
    const int* __restrict__ sF, const int* __restrict__ dF,
    const int* __restrict__ sR, const int* __restrict__ dR,
    const int* __restrict__ cnt, int* __restrict__ beF, int* __restrict__ beR) {
    __shared__ int cur[NBKT2];
    int t = threadIdx.x;
    int which = blockIdx.x >> 9, p = blockIdx.x & 511;
    const int* s; const int* d; int* be; int roff, sub;
    if (which == 0) { s = sF; d = dF; be = beF; roff = 0;   sub = 0; }
    else            { s = sR; d = dR; be = beR; roff = MF_; sub = E2N; }
    for (int b = t; b < NBKT2; b += 256) cur[b] = cnt[roff + (b << 9) + p] - sub;
    __syncthreads();
    int e0 = p * CH;
    for (int e = e0 + t; e < e0 + CH; e += 256) {
        int dd  = d[e];
        int pos = atomicAdd(&cur[dd >> BK_SH], 1);
        be[pos] = s[e] | ((dd & 127) << PACK_SH);
    }
}

__global__ void __launch_bounds__(256) k_bfill1(
    const int* __restrict__ s1, const int* __restrict__ d1,
    const int* __restrict__ cnt, int* __restrict__ be) {
    __shared__ int cur[NBKT1];
    int t = threadIdx.x;
    int p = blockIdx.x;
    for (int b = t; b < NBKT1; b += 256) cur[b] = cnt[2 * MF_ + (b << 9) + p] - 2 * E2N;
    __syncthreads();
    int e0 = p * CH;
    for (int e = e0 + t; e < e0 + CH; e += 256) {
        int dd  = d1[e];
        int pos = atomicAdd(&cur[dd >> BK_SH], 1);
        be[pos] = s1[e] | ((dd & 127) << PACK_SH);
    }
}

// per-bucket: LDS count -> LDS scan -> coalesced off write -> L2-local csr scatter
__device__ __forceinline__ void bcsr_body(const int* __restrict__ bedge,
                                          const int* __restrict__ cnt, int roff, int sub,
                                          int* __restrict__ off, int* __restrict__ csr,
                                          int b, int nbkt, int ntot, int etot) {
    __shared__ int lcnt[128], exs[128], sc[128];
    int t  = threadIdx.x;
    int e0 = cnt[roff + (b << 9)] - sub;
    int e1 = (b + 1 < nbkt) ? cnt[roff + ((b + 1) << 9)] - sub : etot;
    int node0 = b << BK_SH;
    int nloc  = ntot - node0; if (nloc > 128) nloc = 128;
    if (t < 128) lcnt[t] = 0;
    __syncthreads();
    for (int e = e0 + t; e < e1; e += 256)
        atomicAdd(&lcnt[(bedge[e] >> PACK_SH) & 127], 1);
    __syncthreads();
    int cv = (t < 128) ? lcnt[t] : 0;
    if (t < 128) sc[t] = cv;
    __syncthreads();
    for (int o = 1; o < 128; o <<= 1) {
        int add = (t < 128 && t >= o) ? sc[t - o] : 0;
        __syncthreads();
        if (t < 128) sc[t] += add;
        __syncthreads();
    }
    if (t < 128) exs[t] = sc[t] - cv;
    __syncthreads();
    if (t < nloc) off[node0 + t] = e0 + exs[t];
    if (b == nbkt - 1 && t == 0) off[ntot] = e1;
    if (t < 128) lcnt[t] = 0;
    __syncthreads();
    for (int e = e0 + t; e < e1; e += 256) {
        int p   = bedge[e];
        int dl  = (p >> PACK_SH) & 127;
        int pos = e0 + exs[dl] + atomicAdd(&lcnt[dl], 1);
        csr[pos] = p & PACK_MASK;
    }
}

__global__ void __launch_bounds__(256) k_bcsr2(
    const int* beF, const int* beR, const int* __restrict__ cnt,
    int* offF, int* csrF, int* offR, int* csrR) {
    int b = blockIdx.x;
    if (b < NBKT2) bcsr_body(beF, cnt, 0,   0,   offF, csrF, b,         NBKT2, N2N, E2N);
    else           bcsr_body(beR, cnt, MF_, E2N, offR, csrR, b - NBKT2, NBKT2, N2N, E2N);
}

__global__ void __launch_bounds__(256) k_bcsr1(
    const int* be, const int* __restrict__ cnt, int* off, int* csr) {
    bcsr_body(be, cnt, 2 * MF_, 2 * E2N, off, csr, blockIdx.x, NBKT1, NN, E1N);
}

// ---------------- conv1 layer 1: LDS emb table, 4B x-gathers, fp16 out ----------------

__global__ void __launch_bounds__(256) k_sage_emb(
    const int* __restrict__ x, const float* __restrict__ emb,
    __half* __restrict__ hout,
    const int* __restrict__ csr, const int* __restrict__ off,
    const float* __restrict__ wlp, const float* __restrict__ bp,
    const float* __restrict__ wrp, int n) {
    __shared__ float embS[(MAXX + 1) * 32];
    __shared__ float wlT[32][33];
    __shared__ float wrT[32][33];
    int tid = threadIdx.x;
    for (int i = tid; i < (MAXX + 1) * 32; i += 256) embS[i] = emb[i];
    for (int i = tid; i < 1024; i += 256) {
        int j = i >> 5, k = i & 31;
        wlT[k][j] = wlp[i];
        wrT[k][j] = wrp[i];
    }
    __syncthreads();
    int lane = tid & 31;
    int g    = blockIdx.x * 8 + (tid >> 5);
    int G    = gridDim.x * 8;
    for (int node = g; node < n; node += G) {
        int s0 = off[node], s1 = off[node + 1];
        float a0 = 0.f, a1 = 0.f, a2 = 0.f, a3 = 0.f;
        for (int base = s0; base < s1; base += 32) {
            int e  = base + lane;
            int xv = x[csr[e < s1 ? e : s1 - 1]];
            int m  = s1 - base; if (m > 32) m = 32;
            for (int j = 0; j < m; j += 4) {
                #pragma unroll
                for (int k = 0; k < 4; ++k) {
                    int jj = j + k;
                    int xj = __shfl(xv, jj & 31, 32);
                    float v = embS[xj * 32 + lane];
                    float w = (jj < m) ? 1.f : 0.f;
                    switch (k) {
                        case 0: a0 = fmaf(v, w, a0); break;
                        case 1: a1 = fmaf(v, w, a1); break;
                        case 2: a2 = fmaf(v, w, a2); break;
                        case 3: a3 = fmaf(v, w, a3); break;
                    }
                }
            }
        }
        int c = s1 - s0;
        float s = ((a0 + a1) + (a2 + a3)) * (1.0f / (float)(c > 0 ? c : 1));
        float hs = embS[x[node] * 32 + lane];
        float acc = bp[lane];
        #pragma unroll
        for (int k = 0; k < 32; ++k) {
            acc = fmaf(__shfl(s, k, 32), wlT[k][lane], acc);
            acc = fmaf(__shfl(hs, k, 32), wrT[k][lane], acc);
        }
        hout[node * 32 + lane] = __float2half(fmaxf(acc, 0.f));
    }
}

// ---------------- dual-edge fp16 segment mean: 2 edges per gather instr ----------------

__device__ __forceinline__ void seg4_h2(
    const __half2* __restrict__ h2,
    const int* __restrict__ cA, int a0, int a1,
    const int* __restrict__ cB, int b0, int b1,
    const int* __restrict__ cC, int c0, int c1,
    const int* __restrict__ cD, int d0, int d1,
    int lane,
    float& oEA, float& oOA, float& oEB, float& oOB,
    float& oEC, float& oOC, float& oED, float& oOD)
{
    float eA[2] = {0.f, 0.f}, oA[2] = {0.f, 0.f};
    float eB[2] = {0.f, 0.f}, oB[2] = {0.f, 0.f};
    float eC[2] = {0.f, 0.f}, oC[2] = {0.f, 0.f};
    float eD[2] = {0.f, 0.f}, oD[2] = {0.f, 0.f};
    int hsel = (lane >> 4) & 1;
    int col  = lane & 15;
    int pA = a0, pB = b0, pC = c0, pD = d0;
    while (pA < a1 || pB < b1 || pC < c1 || pD < d1) {
        int iA = 0, iB = 0, iC = 0, iD = 0, mA = 0, mB = 0, mC = 0, mD = 0;
        if (pA < a1) { int e = pA + lane; iA = cA[e < a1 ? e : a1 - 1]; mA = a1 - pA; if (mA > 32) mA = 32; }
        if (pB < b1) { int e = pB + lane; iB = cB[e < b1 ? e : b1 - 1]; mB = b1 - pB; if (mB > 32) mB = 32; }
        if (pC < c1) { int e = pC + lane; iC = cC[e < c1 ? e : c1 - 1]; mC = c1 - pC; if (mC > 32) mC = 32; }
        if (pD < d1) { int e = pD + lane; iD = cD[e < d1 ? e : d1 - 1]; mD = d1 - pD; if (mD > 32) mD = 32; }
        int mm = mA > mB ? mA : mB;
        if (mC > mm) mm = mC;
        if (mD > mm) mm = mD;
        for (int j = 0; j < mm; j += 16) {
            __half2 vA[8], vB[8], vC[8], vD[8];
            bool dA = j < mA, dB = j < mB, dC = j < mC, dD = j < mD;
            if (dA) {
                #pragma unroll
                for (int kk = 0; kk < 8; ++kk) {
                    int es = j + 2 * kk + hsel;
                    vA[kk] = h2[__shfl(iA, es & 31, 32) * 16 + col];
                }
            }
            if (dB) {
                #pragma unroll
                for (int kk = 0; kk < 8; ++kk) {
                    int es = j + 2 * kk + hsel;
                    vB[kk] = h2[__shfl(iB, es & 31, 32) * 16 + col];
                }
            }
            if (dC) {
                #pragma unroll
                for (int kk = 0; kk < 8; ++kk) {
                    int es = j + 2 * kk + hsel;
                    vC[kk] = h2[__shfl(iC, es & 31, 32) * 16 + col];
                }
            }
            if (dD) {
                #pragma unroll
                for (int kk = 0; kk < 8; ++kk) {
                    int es = j + 2 * kk + hsel;
                    vD[kk] = h2[__shfl(iD, es & 31, 32) * 16 + col];
                }
            }
            if (dA) {
                #pragma unroll
                for (int kk = 0; kk < 8; ++kk) {
                    int es = j + 2 * kk + hsel;
                    float w = (es < mA) ? 1.f : 0.f;
                    float2 f = __half22float2(vA[kk]);
                    eA[kk & 1] = fmaf(f.x, w, eA[kk & 1]);
                    oA[kk & 1] = fmaf(f.y, w, oA[kk & 1]);
                }
            }
            if (dB) {
                #pragma unroll
                for (int kk = 0; kk < 8; ++kk) {
                    int es = j + 2 * kk + hsel;
                    float w = (es < mB) ? 1.f : 0.f;
                    float2 f = __half22float2(vB[kk]);
                    eB[kk & 1] = fmaf(f.x, w, eB[kk & 1]);
                    oB[kk & 1] = fmaf(f.y, w, oB[kk & 1]);
                }
            }
            if (dC) {
                #pragma unroll
                for (int kk = 0; kk < 8; ++kk) {
                    int es = j + 2 * kk + hsel;
                    float w = (es < mC) ? 1.f : 0.f;
                    float2 f = __half22float2(vC[kk]);
                    eC[kk & 1] = fmaf(f.x, w, eC[kk & 1]);
                    oC[kk & 1] = fmaf(f.y, w, oC[kk & 1]);
                }
            }
            if (dD) {
                #pragma unroll
                for (int kk = 0; kk < 8; ++kk) {
                    int es = j + 2 * kk + hsel;
                    float w = (es < mD) ? 1.f : 0.f;
                    float2 f = __half22float2(vD[kk]);
                    eD[kk & 1] = fmaf(f.x, w, eD[kk & 1]);
                    oD[kk & 1] = fmaf(f.y, w, oD[kk & 1]);
                }
            }
        }
        pA += 32; pB += 32; pC += 32; pD += 32;
    }
    float sE, sO;
    int nA = a1 - a0; float vA_ = 1.f / (float)(nA > 0 ? nA : 1);
    sE = eA[0] + eA[1]; sE += __shfl_xor(sE, 16, 32);
    sO = oA[0] + oA[1]; sO += __shfl_xor(sO, 16, 32);
    oEA = sE * vA_; oOA = sO * vA_;
    int nB = b1 - b0; float vB_ = 1.f / (float)(nB > 0 ? nB : 1);
    sE = eB[0] + eB[1]; sE += __shfl_xor(sE, 16, 32);
    sO = oB[0] + oB[1]; sO += __shfl_xor(sO, 16, 32);
    oEB = sE * vB_; oOB = sO * vB_;
    int nC = c1 - c0; float vC_ = 1.f / (float)(nC > 0 ? nC : 1);
    sE = eC[0] + eC[1]; sE += __shfl_xor(sE, 16, 32);
    sO = oC[0] + oC[1]; sO += __shfl_xor(sO, 16, 32);
    oEC = sE * vC_; oOC = sO * vC_;
    int nD = d1 - d0; float vD_ = 1.f / (float)(nD > 0 ? nD : 1);
    sE = eD[0] + eD[1]; sE += __shfl_xor(sE, 16, 32);
    sO = oD[0] + oD[1]; sO += __shfl_xor(sO, 16, 32);
    oED = sE * vD_; oOD = sO * vD_;
}

// ---------------- sage kernels (fp16 tables, dual-edge gathers) ----------------

__global__ void __launch_bounds__(256) k_sage(
    const __half* __restrict__ hin, __half* __restrict__ hout,
    const int* __restrict__ csr, const int* __restrict__ off,
    const float* __restrict__ wl, const float* __restrict__ bl, const float* __restrict__ wr,
    int n) {
    __shared__ float wlT[32][33];
    __shared__ float wrT[32][33];
    int tid = threadIdx.x;
    for (int idx = tid; idx < 1024; idx += 256) {
        int j = idx >> 5, k = idx & 31;
        wlT[k][j] = wl[idx];
        wrT[k][j] = wr[idx];
    }
    __syncthreads();
    const __half2* h2 = (const __half2*)hin;
    int lane = tid & 31;
    int g    = blockIdx.x * 8 + (tid >> 5);
    int G    = gridDim.x * 8;
    for (int i = 4 * g; i < n; i += 4 * G) {
        int n0 = i, n1 = i + 1, n2 = i + 2, n3 = i + 3;
        float sE0, sO0, sE1, sO1, sE2, sO2, sE3, sO3;
        seg4_h2(h2, csr, off[n0], off[n0 + 1], csr, off[n1], off[n1 + 1],
                csr, off[n2], off[n2 + 1], csr, off[n3], off[n3 + 1],
                lane, sE0, sO0, sE1, sO1, sE2, sO2, sE3, sO3);
        float h0 = __half2float(hin[n0 * 32 + lane]);
        float h1 = __half2float(hin[n1 * 32 + lane]);
        float h2f = __half2float(hin[n2 * 32 + lane]);
        float h3 = __half2float(hin[n3 * 32 + lane]);
        float bb = bl[lane];
        float A0 = bb, A1 = bb, A2 = bb, A3 = bb;
        #pragma unroll
        for (int k = 0; k < 32; ++k) {
            float wlk = wlT[k][lane], wrk = wrT[k][lane];
            float s0k = __shfl((k & 1) ? sO0 : sE0, k >> 1, 32);
            float s1k = __shfl((k & 1) ? sO1 : sE1, k >> 1, 32);
            float s2k = __shfl((k & 1) ? sO2 : sE2, k >> 1, 32);
            float s3k = __shfl((k & 1) ? sO3 : sE3, k >> 1, 32);
            A0 = fmaf(s0k, wlk, A0);
            A0 = fmaf(__shfl(h0, k, 32), wrk, A0);
            A1 = fmaf(s1k, wlk, A1);
            A1 = fmaf(__shfl(h1, k, 32), wrk, A1);
            A2 = fmaf(s2k, wlk, A2);
            A2 = fmaf(__shfl(h2f, k, 32), wrk, A2);
            A3 = fmaf(s3k, wlk, A3);
            A3 = fmaf(__shfl(h3, k, 32), wrk, A3);
        }
        hout[n0 * 32 + lane] = __float2half(fmaxf(A0, 0.f));
        hout[n1 * 32 + lane] = __float2half(fmaxf(A1, 0.f));
        hout[n2 * 32 + lane] = __float2half(fmaxf(A2, 0.f));
        hout[n3 * 32 + lane] = __float2half(fmaxf(A3, 0.f));
    }
}

// fused dual-direction sage; optional per-node mask (mask==nullptr -> all)
__global__ void __launch_bounds__(256) k_sage2(
    const __half* __restrict__ hin, __half* __restrict__ hout,
    const int* __restrict__ csrF, const int* __restrict__ offF,
    const int* __restrict__ csrR, const int* __restrict__ offR,
    const float* __restrict__ wlF, const float* __restrict__ blF, const float* __restrict__ wrF,
    const float* __restrict__ wlR, const float* __restrict__ blR, const float* __restrict__ wrR,
    const int* __restrict__ mask, int n) {
    __shared__ float WLF[32][33], WRF[32][33], WLR[32][33], WRR[32][33];
    int tid = threadIdx.x;
    for (int idx = tid; idx < 1024; idx += 256) {
        int j = idx >> 5, k = idx & 31;
        WLF[k][j] = wlF[idx];
        WRF[k][j] = wrF[idx];
        WLR[k][j] = wlR[idx];
        WRR[k][j] = wrR[idx];
    }
    __syncthreads();
    const __half2* h2 = (const __half2*)hin;
    int lane = tid & 31;
    int g    = blockIdx.x * 8 + (tid >> 5);
    int G    = gridDim.x * 8;
    for (int i = 2 * g; i < n; i += 2 * G) {
        int n0 = i, n1 = i + 1;
        int m0 = mask ? mask[n0] : 1;
        int m1 = mask ? mask[n1] : 1;
        if (!(m0 | m1)) continue;
        int f00 = offF[n0], f01 = offF[n0 + 1], r00 = offR[n0], r01 = offR[n0 + 1];
        int f10 = offF[n1], f11 = offF[n1 + 1], r10 = offR[n1], r11 = offR[n1 + 1];
        if (!m0) { f01 = f00; r01 = r00; }
        if (!m1) { f11 = f10; r11 = r10; }
        float sEF0, sOF0, sER0, sOR0, sEF1, sOF1, sER1, sOR1;
        seg4_h2(h2, csrF, f00, f01, csrR, r00, r01,
                csrF, f10, f11, csrR, r10, r11,
                lane, sEF0, sOF0, sER0, sOR0, sEF1, sOF1, sER1, sOR1);
        float bF = blF[lane], bR = blR[lane];
        if (m0) {
            float h0 = __half2float(hin[n0 * 32 + lane]);
            float aF0 = bF, aR0 = bR;
            #pragma unroll
            for (int k = 0; k < 32; ++k) {
                float fk = __shfl((k & 1) ? sOF0 : sEF0, k >> 1, 32);
                float rk = __shfl((k & 1) ? sOR0 : sER0, k >> 1, 32);
                float hk = __shfl(h0, k, 32);
                aF0 = fmaf(fk, WLF[k][lane], aF0);
                aF0 = fmaf(hk, WRF[k][lane], aF0);
                aR0 = fmaf(rk, WLR[k][lane], aR0);
                aR0 = fmaf(hk, WRR[k][lane], aR0);
            }
            hout[n0 * 32 + lane] = __float2half(fmaxf(aF0, 0.f) + fmaxf(aR0, 0.f));
        }
        if (m1) {
            float h1 = __half2float(hin[n1 * 32 + lane]);
            float aF1 = bF, aR1 = bR;
            #pragma unroll
            for (int k = 0; k < 32; ++k) {
                float fk = __shfl((k & 1) ? sOF1 : sEF1, k >> 1, 32);
                float rk = __shfl((k & 1) ? sOR1 : sER1, k >> 1, 32);
                float hk = __shfl(h1, k, 32);
                aF1 = fmaf(fk, WLF[k][lane], aF1);
                aF1 = fmaf(hk, WRF[k][lane], aF1);
                aR1 = fmaf(rk, WLR[k][lane], aR1);
                aR1 = fmaf(hk, WRR[k][lane], aR1);
            }
            hout[n1 * 32 + lane] = __float2half(fmaxf(aF1, 0.f) + fmaxf(aR1, 0.f));
        }
    }
}

__global__ void k_pair(const __half* __restrict__ h, const int* __restrict__ pos1,
                       __half* __restrict__ hp, int total) {
    int idx = blockIdx.x * blockDim.x + threadIdx.x;
    int stride = gridDim.x * blockDim.x;
    for (; idx < total; idx += stride) {
        int r = idx >> 5, k = idx & 31;
        int a = pos1[2 * r], b = pos1[2 * r + 1];
        hp[idx] = __float2half(__half2float(h[a * 32 + k]) * __half2float(h[b * 32 + k]));
    }
}

__global__ void k_final(const __half* __restrict__ h, const int* __restrict__ pos2,
                        const float* __restrict__ pw, const float* __restrict__ pb,
                        float* __restrict__ out, int m2) {
    int tid  = threadIdx.x;
    int lane = tid & 31;
    int i    = blockIdx.x * 8 + (tid >> 5);
    if (i >= m2) return;
    int p0 = pos2[2 * i], p1 = pos2[2 * i + 1];
    float v = __half2float(h[p0 * 32 + lane]) * __half2float(h[p1 * 32 + lane]) * pw[lane];
    #pragma unroll
    for (int o = 16; o > 0; o >>= 1) v += __shfl_xor(v, o, 32);
    if (lane == 0) out[i] = v + pb[0];
}

// ---------------- launch ----------------

extern "C" void kernel_launch(void* const* d_in, const int* in_sizes, int n_in,
                              void* d_out, int out_size, void* d_ws, size_t ws_size,
                              hipStream_t stream) {
    const int*   x      = (const int*)d_in[0];
    const int*   edge1  = (const int*)d_in[2];
    const int*   edge2  = (const int*)d_in[3];
    const int*   edge2r = (const int*)d_in[4];
    const int*   pos1   = (const int*)d_in[5];
    const int*   pos2   = (const int*)d_in[6];
    const float* emb    = (const float*)d_in[7];
    const float* gw     = (const float*)d_in[8];
    const float* gb     = (const float*)d_in[9];
    const float* gms    = (const float*)d_in[10];
    const float* c1wl   = (const float*)d_in[11];
    const float* c1bl   = (const float*)d_in[12];
    const float* c1wr   = (const float*)d_in[13];
    const float* c2wl   = (const float*)d_in[14];
    const float* c2bl   = (const float*)d_in[15];
    const float* c2wr   = (const float*)d_in[16];
    const float* c2rwl  = (const float*)d_in[17];
    const float* c2rbl  = (const float*)d_in[18];
    const float* c2rwr  = (const float*)d_in[19];
    const float* pw     = (const float*)d_in[20];
    const float* pb     = (const float*)d_in[21];
    float* out = (float*)d_out;

    char* ws = (char*)d_ws;
    __half* hA   = (__half*)(ws + OFF_HA);
    __half* hB   = (__half*)(ws + OFF_HB);
    int*   cnt   = (int*)(ws + OFF_HB);          // 8MB overlay on hB, dead before k_sage_emb
    int*   csr1  = (int*)(ws + OFF_CSR1);
    int*   csr2  = (int*)(ws + OFF_CSR2);
    int*   csr2r = (int*)(ws + OFF_CSR2R);
    int*   off1  = (int*)(ws + OFF_OFF1);
    int*   off2  = (int*)(ws + OFF_OFF2);
    int*   off2r = (int*)(ws + OFF_OFF2R);
    int*   bsum  = (int*)(ws + OFF_BSUM);
    int*   hist  = (int*)(ws + OFF_HIST);
    float* wlp   = (float*)(ws + OFF_WLP);
    float* wrp   = (float*)(ws + OFF_WRP);
    float* bp    = (float*)(ws + OFF_BP);
    int*   mark  = (int*)(ws + OFF_MARK);

    // temp bucketed-edge arrays overlay hA (dead until k_sage writes hA)
    int* beF = (int*)(ws + OFF_HA);
    int* beR = (int*)(ws + OFF_HA + 12800000);
    int* be1 = (int*)(ws + OFF_HA);

    hipMemsetAsync(hist, 0, 512, stream);
    hipMemsetAsync(mark, 0, N2N * sizeof(int), stream);

    // --- GraphNorm stats from x-histogram + layer-1 weight fold; pos2 mark ---
    k_histx<<<256, 256, 0, stream>>>(x, hist, NN);
    k_prep<<<1, 256, 0, stream>>>(hist, emb, gw, gb, gms, c1wl, c1bl, c1wr, wlp, wrp, bp);
    k_mark<<<256, 256, 0, stream>>>(pos2, mark, MN);

    // --- CSR build: histogram -> scan -> bin (LDS cursors) -> per-bucket refine ---
    k_hist<<<3 * P_PART, 256, 0, stream>>>(edge2 + E2N, edge2r + E2N, edge1 + E1N, cnt);
    k_scanA<<<SCAN_NB, 256, 0, stream>>>(cnt, bsum);
    k_scanB<<<1, 256, 0, stream>>>(bsum, SCAN_NB);
    k_scanC<<<SCAN_NB, 256, 0, stream>>>(cnt, bsum);
    k_bfillFR<<<2 * P_PART, 256, 0, stream>>>(edge2, edge2 + E2N, edge2r, edge2r + E2N,
                                              cnt, beF, beR);
    k_bcsr2<<<2 * NBKT2, 256, 0, stream>>>(beF, beR, cnt, off2, csr2, off2r, csr2r);
    k_bfill1<<<P_PART, 256, 0, stream>>>(edge1, edge1 + E1N, cnt, be1);
    k_bcsr1<<<NBKT1, 256, 0, stream>>>(be1, cnt, off1, csr1);

    // --- conv1 layer 1: direct from emb via LDS -> h1 fp16 (clobbers cnt) ---
    k_sage_emb<<<6250, 256, 0, stream>>>(x, emb, hB, csr1, off1, wlp, bp, wrp, NN);

    // --- conv1 layer 2: hB -> hA fp16 (clobbers be temp, now dead) ---
    k_sage<<<2048, 256, 0, stream>>>(hB, hA, csr1, off1,
                                     c1wl + 1024, c1bl + 32, c1wr + 1024, NN);

    // --- pair features: hA (N rows) -> hB (N2 rows fp16; csr1 now dead) ---
    k_pair<<<2048, 256, 0, stream>>>(hA, pos1, hB, N2N * 32);

    // --- conv2 layer 1 (all nodes): hB -> hA ---
    k_sage2<<<2048, 256, 0, stream>>>(hB, hA, csr2, off2, csr2r, off2r,
        c2wl, c2bl, c2wr, c2rwl, c2rbl, c2rwr, (const int*)nullptr, N2N);

    // --- conv2 layer 2 (only pos2-referenced nodes): hA -> hB ---
    k_sage2<<<2048, 256, 0, stream>>>(hA, hB, csr2, off2, csr2r, off2r,
        c2wl + 1024, c2bl + 32, c2wr + 1024, c2rwl + 1024, c2rbl + 32, c2rwr + 1024,
        mark, N2N);

    // --- head ---
    k_final<<<(MN / 2) / 8, 256, 0, stream>>>(hB, pos2, pw, pb, out, MN / 2);
}